// Round 6
// baseline (555.565 us; speedup 1.0000x reference)
//
#include <hip/hip_runtime.h>
#include <hip/hip_bf16.h>

typedef __attribute__((ext_vector_type(8))) short s16x8;
typedef __attribute__((ext_vector_type(4))) float f32x4;

#define T_TOK 8192
#define H_DIM 512
#define I_DIM 1024

static __device__ __forceinline__ unsigned short f2bf(float f){
  unsigned int b = __builtin_bit_cast(unsigned int, f);
  b += 0x7FFFu + ((b >> 16) & 1u);           // round-to-nearest-even
  return (unsigned short)(b >> 16);
}

// ---- per-expert transpose + convert: in [E][R][C] f32 -> out [E][C][R] bf16 ----
__global__ void transpose_cvt(const float* __restrict__ in, unsigned short* __restrict__ out,
                              int R, int C){
  __shared__ unsigned short tile[64][72];
  int e = blockIdx.z;
  const float* src = in + (size_t)e * R * C;
  unsigned short* dst = out + (size_t)e * R * C;
  int r0 = blockIdx.y * 64, c0 = blockIdx.x * 64;
  int tr = threadIdx.x >> 4;           // 0..15
  int tc = (threadIdx.x & 15) * 4;     // 0..60
  #pragma unroll
  for (int i = 0; i < 4; i++){
    int r = tr + i * 16;
    float4 v = *reinterpret_cast<const float4*>(src + (size_t)(r0 + r) * C + c0 + tc);
    tile[tc + 0][r] = f2bf(v.x);
    tile[tc + 1][r] = f2bf(v.y);
    tile[tc + 2][r] = f2bf(v.z);
    tile[tc + 3][r] = f2bf(v.w);
  }
  __syncthreads();
  #pragma unroll
  for (int i = 0; i < 4; i++){
    int cl = tr + i * 16;              // col of original = row of transposed
    ushort4 o;
    o.x = tile[cl][tc + 0]; o.y = tile[cl][tc + 1];
    o.z = tile[cl][tc + 2]; o.w = tile[cl][tc + 3];
    *reinterpret_cast<ushort4*>(dst + (size_t)(c0 + cl) * R + r0 + tc) = o;
  }
}

// ---- router: logits (fp32) + top-2 + fused x->bf16 conversion ----
__global__ void router_kernel(const float* __restrict__ x, const float* __restrict__ gw,
                              float* __restrict__ logits_out,
                              int* __restrict__ eab, float* __restrict__ wab,
                              unsigned short* __restrict__ xb){
  int wave = threadIdx.x >> 6;
  int lane = threadIdx.x & 63;
  int t = blockIdx.x * 4 + wave;
  const float* xr = x + (size_t)t * H_DIM;
  float xv[8];
  *reinterpret_cast<float4*>(&xv[0]) = *reinterpret_cast<const float4*>(xr + lane * 8);
  *reinterpret_cast<float4*>(&xv[4]) = *reinterpret_cast<const float4*>(xr + lane * 8 + 4);
  s16x8 xo;
  #pragma unroll
  for (int m = 0; m < 8; m++) xo[m] = (short)f2bf(xv[m]);
  *reinterpret_cast<s16x8*>(xb + (size_t)t * H_DIM + lane * 8) = xo;

  float l[8];
  #pragma unroll
  for (int e = 0; e < 8; e++){
    const float* g = gw + e * H_DIM + lane * 8;
    float4 g0 = *reinterpret_cast<const float4*>(g);
    float4 g1 = *reinterpret_cast<const float4*>(g + 4);
    float s = xv[0]*g0.x + xv[1]*g0.y + xv[2]*g0.z + xv[3]*g0.w
            + xv[4]*g1.x + xv[5]*g1.y + xv[6]*g1.z + xv[7]*g1.w;
    #pragma unroll
    for (int o = 32; o >= 1; o >>= 1) s += __shfl_xor(s, o);
    l[e] = s;
  }
  if (lane == 0){
    float4 L0 = make_float4(l[0], l[1], l[2], l[3]);
    float4 L1 = make_float4(l[4], l[5], l[6], l[7]);
    *reinterpret_cast<float4*>(logits_out + (size_t)t * 8)     = L0;
    *reinterpret_cast<float4*>(logits_out + (size_t)t * 8 + 4) = L1;
    float m = l[0];
    #pragma unroll
    for (int e = 1; e < 8; e++) m = fmaxf(m, l[e]);
    float p[8]; float Z = 0.f;
    #pragma unroll
    for (int e = 0; e < 8; e++){ p[e] = expf(l[e] - m); Z += p[e]; }
    int a = 0;
    #pragma unroll
    for (int e = 1; e < 8; e++) if (p[e] > p[a]) a = e;   // earliest max: matches top_k
    int b = (a == 0) ? 1 : 0;
    #pragma unroll
    for (int e = 0; e < 8; e++) if (e != a && p[e] > p[b]) b = e;
    float pa = p[a] / Z, pb = p[b] / Z;
    float inv = 0.5f / (pa + pb + 1e-20f);                // norm_topk + /TOP_K
    eab[t] = a | (b << 8);
    *reinterpret_cast<float2*>(wab + (size_t)t * 2) = make_float2(pa * inv, pb * inv);
  }
}

// ---- router stage 2: ballot-aggregated scatter into per-expert lists ----
__global__ __launch_bounds__(256) void scatter_kernel(
    const int* __restrict__ eab, const float* __restrict__ wab,
    int* __restrict__ cnt, int* __restrict__ tok, float* __restrict__ wgt){
  __shared__ int wcnt[8][8];
  __shared__ int lbase[8][8];
  __shared__ int gbase[8];
  int tid = threadIdx.x;
  int wave = tid >> 6, lane = tid & 63;
  int t = blockIdx.x * 256 + tid;
  int ee = eab[t];
  int ea = ee & 0xff, eb = ee >> 8;
  float2 wv = *reinterpret_cast<const float2*>(wab + (size_t)t * 2);
  unsigned long long mlt = (1ull << lane) - 1ull;
  int rankA = 0, rankB = 0;
  #pragma unroll
  for (int e = 0; e < 8; e++){
    unsigned long long mA = __ballot(ea == e);
    unsigned long long mB = __ballot(eb == e);
    if (ea == e) rankA = __popcll(mA & mlt);
    if (eb == e) rankB = __popcll(mB & mlt);
    if (lane == 0){
      wcnt[wave * 2 + 0][e] = __popcll(mA);
      wcnt[wave * 2 + 1][e] = __popcll(mB);
    }
  }
  __syncthreads();
  if (tid < 8){
    int s = 0;
    #pragma unroll
    for (int w = 0; w < 8; w++){ lbase[w][tid] = s; s += wcnt[w][tid]; }
    gbase[tid] = atomicAdd(&cnt[tid], s);
  }
  __syncthreads();
  int ia = gbase[ea] + lbase[wave * 2 + 0][ea] + rankA;
  tok[ea * T_TOK + ia] = t; wgt[ea * T_TOK + ia] = wv.x;
  int ib = gbase[eb] + lbase[wave * 2 + 1][eb] + rankB;
  tok[eb * T_TOK + ib] = t; wgt[eb * T_TOK + ib] = wv.y;
}

__global__ void prefix_kernel(const int* __restrict__ cnt, int* __restrict__ off){
  if (threadIdx.x == 0){
    int s = 0;
    for (int e = 0; e < 8; e++){ off[e] = s; s += cnt[e]; }
  }
}

// ---- GEMM1: h = relu(gather(xb) @ w1t^T + b1). Reg-staged padded LDS + T14 issue-early ----
__global__ __launch_bounds__(256) void gemm1_kernel(
    const unsigned short* __restrict__ xb, const unsigned short* __restrict__ w1t,
    const float* __restrict__ b1,
    const int* __restrict__ cnt, const int* __restrict__ off,
    const int* __restrict__ tok,
    unsigned short* __restrict__ h_buf){
  int e  = blockIdx.x >> 6;
  int tm = blockIdx.x & 63;
  int n_e = cnt[e];
  int base = tm * 128;
  if (base >= n_e) return;
  int n0 = blockIdx.y * 128;

  __shared__ unsigned short As[128 * 72];
  __shared__ unsigned short Bs[128 * 72];

  int tid = threadIdx.x;
  int lane = tid & 63, wid = tid >> 6;
  int cc = (tid & 7) * 8;            // staging column (elements)
  int rr = tid >> 3;                 // staging row base (0..31), +32 per chunk

  // per-thread staging source pointers (4 rows per operand)
  const unsigned short* a_src[4];
  const unsigned short* b_src[4];
  const unsigned short* Bg = w1t + ((size_t)e * I_DIM + n0) * H_DIM;
  #pragma unroll
  for (int j = 0; j < 4; j++){
    int r = rr + j * 32;
    int gr = base + r; if (gr >= n_e) gr = n_e - 1;
    a_src[j] = xb + (size_t)tok[e * T_TOK + gr] * H_DIM + cc;
    b_src[j] = Bg + (size_t)r * H_DIM + cc;
  }

  int wm = (wid >> 1) * 64, wn = (wid & 1) * 64;
  int rfrag = lane & 15;
  int koff  = (lane >> 4) * 8;

  f32x4 acc[4][4] = {};
  int4 ra[4], rb[4];
  #pragma unroll
  for (int j = 0; j < 4; j++){
    ra[j] = *reinterpret_cast<const int4*>(a_src[j]);
    rb[j] = *reinterpret_cast<const int4*>(b_src[j]);
  }

  for (int k0 = 0; k0 < H_DIM; k0 += 64){
    #pragma unroll
    for (int j = 0; j < 4; j++){
      int r = rr + j * 32;
      *reinterpret_cast<int4*>(&As[r * 72 + cc]) = ra[j];
      *reinterpret_cast<int4*>(&Bs[r * 72 + cc]) = rb[j];
    }
    __syncthreads();
    if (k0 + 64 < H_DIM){
      #pragma unroll
      for (int j = 0; j < 4; j++){
        ra[j] = *reinterpret_cast<const int4*>(a_src[j] + k0 + 64);
        rb[j] = *reinterpret_cast<const int4*>(b_src[j] + k0 + 64);
      }
    }
    #pragma unroll
    for (int kk = 0; kk < 2; kk++){
      s16x8 af[4], bfr[4];
      #pragma unroll
      for (int fm = 0; fm < 4; fm++)
        af[fm] = *reinterpret_cast<const s16x8*>(&As[(wm + fm * 16 + rfrag) * 72 + kk * 32 + koff]);
      #pragma unroll
      for (int fn = 0; fn < 4; fn++)
        bfr[fn] = *reinterpret_cast<const s16x8*>(&Bs[(wn + fn * 16 + rfrag) * 72 + kk * 32 + koff]);
      #pragma unroll
      for (int fm = 0; fm < 4; fm++){
        #pragma unroll
        for (int fn = 0; fn < 4; fn++)
          acc[fm][fn] = __builtin_amdgcn_mfma_f32_16x16x32_bf16(af[fm], bfr[fn], acc[fm][fn], 0, 0, 0);
      }
    }
    __syncthreads();
  }

  int offe = off[e];
  int rbase = wm + (lane >> 4) * 4;
  #pragma unroll
  for (int fm = 0; fm < 4; fm++){
    #pragma unroll
    for (int j = 0; j < 4; j++){
      int gr = base + rbase + fm * 16 + j;
      if (gr < n_e){
        #pragma unroll
        for (int fn = 0; fn < 4; fn++){
          int col = n0 + wn + fn * 16 + rfrag;
          float h = acc[fm][fn][j] + b1[e * I_DIM + col];
          h_buf[(size_t)(offe + gr) * I_DIM + col] = f2bf(fmaxf(h, 0.f));
        }
      }
    }
  }
}

// ---- GEMM2: y = h @ w2t^T (+b2 on kh==0); out[t] += w*y. Split-K x2, reg-staged + T14 ----
__global__ __launch_bounds__(256) void gemm2_kernel(
    const unsigned short* __restrict__ h_buf, const unsigned short* __restrict__ w2t,
    const float* __restrict__ b2,
    const int* __restrict__ cnt, const int* __restrict__ off,
    const int* __restrict__ tok, const float* __restrict__ wgt,
    float* __restrict__ out){
  int e  = blockIdx.x >> 6;
  int tm = blockIdx.x & 63;
  int n_e = cnt[e];
  int base = tm * 128;
  if (base >= n_e) return;
  int n0 = blockIdx.y * 128;
  int kh = blockIdx.z;                 // split-K half

  __shared__ unsigned short As[128 * 72];
  __shared__ unsigned short Bs[128 * 72];
  __shared__ int tok_s[128];
  __shared__ float wgt_s[128];

  int tid = threadIdx.x;
  int offe = off[e];
  if (tid < 128){
    int gr = base + tid;
    int gi = (gr < n_e) ? gr : (n_e - 1);
    tok_s[tid] = tok[e * T_TOK + gi];
    wgt_s[tid] = wgt[e * T_TOK + gi];
  }

  int lane = tid & 63, wid = tid >> 6;
  int cc = (tid & 7) * 8;
  int rr = tid >> 3;

  const unsigned short* a_src[4];
  const unsigned short* b_src[4];
  const unsigned short* Bg = w2t + ((size_t)e * H_DIM + n0) * I_DIM;
  #pragma unroll
  for (int j = 0; j < 4; j++){
    int r = rr + j * 32;
    int gr = base + r; if (gr >= n_e) gr = n_e - 1;
    a_src[j] = h_buf + (size_t)(offe + gr) * I_DIM + cc;
    b_src[j] = Bg + (size_t)r * I_DIM + cc;
  }

  int wm = (wid >> 1) * 64, wn = (wid & 1) * 64;
  int rfrag = lane & 15;
  int koff  = (lane >> 4) * 8;

  f32x4 acc[4][4] = {};
  int kbeg = kh * 512, kend = kbeg + 512;
  int4 ra[4], rb[4];
  #pragma unroll
  for (int j = 0; j < 4; j++){
    ra[j] = *reinterpret_cast<const int4*>(a_src[j] + kbeg);
    rb[j] = *reinterpret_cast<const int4*>(b_src[j] + kbeg);
  }

  for (int k0 = kbeg; k0 < kend; k0 += 64){
    #pragma unroll
    for (int j = 0; j < 4; j++){
      int r = rr + j * 32;
      *reinterpret_cast<int4*>(&As[r * 72 + cc]) = ra[j];
      *reinterpret_cast<int4*>(&Bs[r * 72 + cc]) = rb[j];
    }
    __syncthreads();
    if (k0 + 64 < kend){
      #pragma unroll
      for (int j = 0; j < 4; j++){
        ra[j] = *reinterpret_cast<const int4*>(a_src[j] + k0 + 64);
        rb[j] = *reinterpret_cast<const int4*>(b_src[j] + k0 + 64);
      }
    }
    #pragma unroll
    for (int kk = 0; kk < 2; kk++){
      s16x8 af[4], bfr[4];
      #pragma unroll
      for (int fm = 0; fm < 4; fm++)
        af[fm] = *reinterpret_cast<const s16x8*>(&As[(wm + fm * 16 + rfrag) * 72 + kk * 32 + koff]);
      #pragma unroll
      for (int fn = 0; fn < 4; fn++)
        bfr[fn] = *reinterpret_cast<const s16x8*>(&Bs[(wn + fn * 16 + rfrag) * 72 + kk * 32 + koff]);
      #pragma unroll
      for (int fm = 0; fm < 4; fm++){
        #pragma unroll
        for (int fn = 0; fn < 4; fn++)
          acc[fm][fn] = __builtin_amdgcn_mfma_f32_16x16x32_bf16(af[fm], bfr[fn], acc[fm][fn], 0, 0, 0);
      }
    }
    __syncthreads();
  }

  int rbase = wm + (lane >> 4) * 4;
  #pragma unroll
  for (int fm = 0; fm < 4; fm++){
    #pragma unroll
    for (int j = 0; j < 4; j++){
      int row_l = rbase + fm * 16 + j;
      int gr = base + row_l;
      if (gr < n_e){
        int t = tok_s[row_l];
        float wv = wgt_s[row_l];
        #pragma unroll
        for (int fn = 0; fn < 4; fn++){
          int col = n0 + wn + fn * 16 + rfrag;
          float y = acc[fm][fn][j] + (kh == 0 ? b2[e * H_DIM + col] : 0.f);
          atomicAdd(out + (size_t)t * H_DIM + col, wv * y);
        }
      }
    }
  }
}

extern "C" void kernel_launch(void* const* d_in, const int* in_sizes, int n_in,
                              void* d_out, int out_size, void* d_ws, size_t ws_size,
                              hipStream_t stream){
  const float* x  = (const float*)d_in[0];
  const float* gw = (const float*)d_in[1];
  const float* w1 = (const float*)d_in[2];
  const float* b1 = (const float*)d_in[3];
  const float* w2 = (const float*)d_in[4];
  const float* b2 = (const float*)d_in[5];
  float* out = (float*)d_out;

  char* ws = (char*)d_ws;
  int*   cnt = (int*)(ws);
  int*   off = (int*)(ws + 32);
  int*   tok = (int*)(ws + 64);                               // 256 KB
  float* wgt = (float*)(ws + 64 + 262144);                    // 256 KB
  unsigned short* xb    = (unsigned short*)(ws + 524352);     // 8 MB
  unsigned short* w1t   = (unsigned short*)(ws + 8912960);    // 8 MB  [E][I][H]
  unsigned short* w2t   = (unsigned short*)(ws + 17301568);   // 8 MB  [E][H][I]
  unsigned short* h_buf = (unsigned short*)(ws + 25690176);   // 32 MB
  int*   eab = (int*)(ws + 59244608);                         // 32 KB
  float* wab = (float*)(ws + 59277376);                       // 64 KB

  hipMemsetAsync(d_out, 0, (size_t)out_size * 4, stream);
  hipMemsetAsync(cnt, 0, 64, stream);

  transpose_cvt<<<dim3(16, 8, 8), 256, 0, stream>>>(w1, w1t, 512, 1024);
  transpose_cvt<<<dim3(8, 16, 8), 256, 0, stream>>>(w2, w2t, 1024, 512);

  float* logits_out = out + (size_t)T_TOK * H_DIM;
  router_kernel<<<2048, 256, 0, stream>>>(x, gw, logits_out, eab, wab, xb);
  scatter_kernel<<<32, 256, 0, stream>>>(eab, wab, cnt, tok, wgt);
  prefix_kernel<<<1, 64, 0, stream>>>(cnt, off);

  gemm1_kernel<<<dim3(512, 8), 256, 0, stream>>>(xb, w1t, b1, cnt, off, tok, h_buf);
  gemm2_kernel<<<dim3(512, 4, 2), 256, 0, stream>>>(h_buf, w2t, b2, cnt, off, tok, wgt, out);
}

// Round 9
// 237.133 us; speedup vs baseline: 2.3428x; 2.3428x over previous
//
#include <hip/hip_runtime.h>
#include <hip/hip_bf16.h>

typedef __attribute__((ext_vector_type(8))) short s16x8;
typedef __attribute__((ext_vector_type(4))) float f32x4;

#define T_TOK 8192
#define H_DIM 512
#define I_DIM 1024

static __device__ __forceinline__ unsigned short f2bf(float f){
  unsigned int b = __builtin_bit_cast(unsigned int, f);
  b += 0x7FFFu + ((b >> 16) & 1u);           // round-to-nearest-even
  return (unsigned short)(b >> 16);
}

// ---- per-expert transpose + convert: in [E][R][C] f32 -> out [E][C][R] bf16 ----
__global__ void transpose_cvt(const float* __restrict__ in, unsigned short* __restrict__ out,
                              int R, int C){
  __shared__ unsigned short tile[64][72];
  int e = blockIdx.z;
  const float* src = in + (size_t)e * R * C;
  unsigned short* dst = out + (size_t)e * R * C;
  int r0 = blockIdx.y * 64, c0 = blockIdx.x * 64;
  int tr = threadIdx.x >> 4;           // 0..15
  int tc = (threadIdx.x & 15) * 4;     // 0..60
  #pragma unroll
  for (int i = 0; i < 4; i++){
    int r = tr + i * 16;
    float4 v = *reinterpret_cast<const float4*>(src + (size_t)(r0 + r) * C + c0 + tc);
    tile[tc + 0][r] = f2bf(v.x);
    tile[tc + 1][r] = f2bf(v.y);
    tile[tc + 2][r] = f2bf(v.z);
    tile[tc + 3][r] = f2bf(v.w);
  }
  __syncthreads();
  #pragma unroll
  for (int i = 0; i < 4; i++){
    int cl = tr + i * 16;              // col of original = row of transposed
    ushort4 o;
    o.x = tile[cl][tc + 0]; o.y = tile[cl][tc + 1];
    o.z = tile[cl][tc + 2]; o.w = tile[cl][tc + 3];
    *reinterpret_cast<ushort4*>(dst + (size_t)(c0 + cl) * R + r0 + tc) = o;
  }
}

// ---- router: logits (fp32) + top-2 + fused x->bf16 conversion ----
__global__ void router_kernel(const float* __restrict__ x, const float* __restrict__ gw,
                              float* __restrict__ logits_out,
                              int* __restrict__ eab, float* __restrict__ wab,
                              unsigned short* __restrict__ xb){
  int wave = threadIdx.x >> 6;
  int lane = threadIdx.x & 63;
  int t = blockIdx.x * 4 + wave;
  const float* xr = x + (size_t)t * H_DIM;
  float xv[8];
  *reinterpret_cast<float4*>(&xv[0]) = *reinterpret_cast<const float4*>(xr + lane * 8);
  *reinterpret_cast<float4*>(&xv[4]) = *reinterpret_cast<const float4*>(xr + lane * 8 + 4);
  s16x8 xo;
  #pragma unroll
  for (int m = 0; m < 8; m++) xo[m] = (short)f2bf(xv[m]);
  *reinterpret_cast<s16x8*>(xb + (size_t)t * H_DIM + lane * 8) = xo;

  float l[8];
  #pragma unroll
  for (int e = 0; e < 8; e++){
    const float* g = gw + e * H_DIM + lane * 8;
    float4 g0 = *reinterpret_cast<const float4*>(g);
    float4 g1 = *reinterpret_cast<const float4*>(g + 4);
    float s = xv[0]*g0.x + xv[1]*g0.y + xv[2]*g0.z + xv[3]*g0.w
            + xv[4]*g1.x + xv[5]*g1.y + xv[6]*g1.z + xv[7]*g1.w;
    #pragma unroll
    for (int o = 32; o >= 1; o >>= 1) s += __shfl_xor(s, o);
    l[e] = s;
  }
  if (lane == 0){
    float4 L0 = make_float4(l[0], l[1], l[2], l[3]);
    float4 L1 = make_float4(l[4], l[5], l[6], l[7]);
    *reinterpret_cast<float4*>(logits_out + (size_t)t * 8)     = L0;
    *reinterpret_cast<float4*>(logits_out + (size_t)t * 8 + 4) = L1;
    float m = l[0];
    #pragma unroll
    for (int e = 1; e < 8; e++) m = fmaxf(m, l[e]);
    float p[8]; float Z = 0.f;
    #pragma unroll
    for (int e = 0; e < 8; e++){ p[e] = expf(l[e] - m); Z += p[e]; }
    int a = 0;
    #pragma unroll
    for (int e = 1; e < 8; e++) if (p[e] > p[a]) a = e;   // earliest max: matches top_k
    int b = (a == 0) ? 1 : 0;
    #pragma unroll
    for (int e = 0; e < 8; e++) if (e != a && p[e] > p[b]) b = e;
    float pa = p[a] / Z, pb = p[b] / Z;
    float inv = 0.5f / (pa + pb + 1e-20f);                // norm_topk + /TOP_K
    eab[t] = a | (b << 8);
    *reinterpret_cast<float2*>(wab + (size_t)t * 2) = make_float2(pa * inv, pb * inv);
  }
}

// ---- router stage 2: ballot-aggregated scatter into per-expert lists ----
__global__ __launch_bounds__(256) void scatter_kernel(
    const int* __restrict__ eab, const float* __restrict__ wab,
    int* __restrict__ cnt, int* __restrict__ tok, float* __restrict__ wgt){
  __shared__ int wcnt[8][8];
  __shared__ int lbase[8][8];
  __shared__ int gbase[8];
  int tid = threadIdx.x;
  int wave = tid >> 6, lane = tid & 63;
  int t = blockIdx.x * 256 + tid;
  int ee = eab[t];
  int ea = ee & 0xff, eb = ee >> 8;
  float2 wv = *reinterpret_cast<const float2*>(wab + (size_t)t * 2);
  unsigned long long mlt = (1ull << lane) - 1ull;
  int rankA = 0, rankB = 0;
  #pragma unroll
  for (int e = 0; e < 8; e++){
    unsigned long long mA = __ballot(ea == e);
    unsigned long long mB = __ballot(eb == e);
    if (ea == e) rankA = __popcll(mA & mlt);
    if (eb == e) rankB = __popcll(mB & mlt);
    if (lane == 0){
      wcnt[wave * 2 + 0][e] = __popcll(mA);
      wcnt[wave * 2 + 1][e] = __popcll(mB);
    }
  }
  __syncthreads();
  if (tid < 8){
    int s = 0;
    #pragma unroll
    for (int w = 0; w < 8; w++){ lbase[w][tid] = s; s += wcnt[w][tid]; }
    gbase[tid] = atomicAdd(&cnt[tid], s);
  }
  __syncthreads();
  int ia = gbase[ea] + lbase[wave * 2 + 0][ea] + rankA;
  tok[ea * T_TOK + ia] = t; wgt[ea * T_TOK + ia] = wv.x;
  int ib = gbase[eb] + lbase[wave * 2 + 1][eb] + rankB;
  tok[eb * T_TOK + ib] = t; wgt[eb * T_TOK + ib] = wv.y;
}

// ---- build per-expert offsets + exact 64-row tile map ----
__global__ void build_tiles(const int* __restrict__ cnt, int* __restrict__ off,
                            int* __restrict__ tmap){
  if (threadIdx.x == 0){
    int s = 0;
    for (int e = 0; e < 8; e++){ off[e] = s; s += cnt[e]; }
    int nt = 0;
    for (int e = 0; e < 8; e++)
      for (int b = 0; b < cnt[e]; b += 64)
        tmap[nt++] = (b << 3) | e;      // pack: base<<3 | expert
    off[8] = nt;                        // total tiles (<= 264)
  }
}

// ---- GEMM1: h = relu(gather(xb) @ w1t^T + b1). 64x128 tile, 4 waves of 32x64 ----
__global__ __launch_bounds__(256) void gemm1_kernel(
    const unsigned short* __restrict__ xb, const unsigned short* __restrict__ w1t,
    const float* __restrict__ b1,
    const int* __restrict__ cnt, const int* __restrict__ off,
    const int* __restrict__ tok, const int* __restrict__ tmap,
    unsigned short* __restrict__ h_buf){
  int nt = off[8];
  int tile = blockIdx.x;
  if (tile >= nt) return;
  int tmv = tmap[tile];
  int e = tmv & 7, base = tmv >> 3;
  int n_e = cnt[e];
  int offe = off[e];
  int n0 = blockIdx.y * 128;

  __shared__ unsigned short As[64 * 72];
  __shared__ unsigned short Bs[128 * 72];

  int tid = threadIdx.x;
  int lane = tid & 63, wid = tid >> 6;
  int cc = (tid & 7) * 8;            // staging column (elements)
  int sr = tid >> 3;                 // staging row base 0..31

  const unsigned short* a_src[2];
  #pragma unroll
  for (int j = 0; j < 2; j++){
    int gr = base + sr + j * 32; if (gr >= n_e) gr = n_e - 1;
    a_src[j] = xb + (size_t)tok[e * T_TOK + gr] * H_DIM + cc;
  }
  const unsigned short* b_src[4];
  const unsigned short* Bg = w1t + ((size_t)e * I_DIM + n0) * H_DIM;
  #pragma unroll
  for (int j = 0; j < 4; j++)
    b_src[j] = Bg + (size_t)(sr + j * 32) * H_DIM + cc;

  int wm = (wid >> 1) * 32, wn = (wid & 1) * 64;
  int rfrag = lane & 15;
  int koff  = (lane >> 4) * 8;

  f32x4 acc[2][4] = {};

  for (int k0 = 0; k0 < H_DIM; k0 += 64){
    #pragma unroll
    for (int j = 0; j < 2; j++)
      *reinterpret_cast<int4*>(&As[(sr + j * 32) * 72 + cc]) =
          *reinterpret_cast<const int4*>(a_src[j] + k0);
    #pragma unroll
    for (int j = 0; j < 4; j++)
      *reinterpret_cast<int4*>(&Bs[(sr + j * 32) * 72 + cc]) =
          *reinterpret_cast<const int4*>(b_src[j] + k0);
    __syncthreads();
    #pragma unroll
    for (int kk = 0; kk < 2; kk++){
      s16x8 af[2], bfr[4];
      #pragma unroll
      for (int fm = 0; fm < 2; fm++)
        af[fm] = *reinterpret_cast<const s16x8*>(&As[(wm + fm * 16 + rfrag) * 72 + kk * 32 + koff]);
      #pragma unroll
      for (int fn = 0; fn < 4; fn++)
        bfr[fn] = *reinterpret_cast<const s16x8*>(&Bs[(wn + fn * 16 + rfrag) * 72 + kk * 32 + koff]);
      #pragma unroll
      for (int fm = 0; fm < 2; fm++){
        #pragma unroll
        for (int fn = 0; fn < 4; fn++)
          acc[fm][fn] = __builtin_amdgcn_mfma_f32_16x16x32_bf16(af[fm], bfr[fn], acc[fm][fn], 0, 0, 0);
      }
    }
    __syncthreads();
  }

  int rbase = wm + (lane >> 4) * 4;
  #pragma unroll
  for (int fm = 0; fm < 2; fm++){
    #pragma unroll
    for (int j = 0; j < 4; j++){
      int gr = base + rbase + fm * 16 + j;
      if (gr < n_e){
        #pragma unroll
        for (int fn = 0; fn < 4; fn++){
          int col = n0 + wn + fn * 16 + rfrag;
          float h = acc[fm][fn][j] + b1[e * I_DIM + col];
          h_buf[(size_t)(offe + gr) * I_DIM + col] = f2bf(fmaxf(h, 0.f));
        }
      }
    }
  }
}

// ---- GEMM2: y = h @ w2t^T + b2; out[t] += w * y. 64x128 tile, no split-K ----
__global__ __launch_bounds__(256) void gemm2_kernel(
    const unsigned short* __restrict__ h_buf, const unsigned short* __restrict__ w2t,
    const float* __restrict__ b2,
    const int* __restrict__ cnt, const int* __restrict__ off,
    const int* __restrict__ tok, const float* __restrict__ wgt,
    const int* __restrict__ tmap,
    float* __restrict__ out){
  int nt = off[8];
  int tile = blockIdx.x;
  if (tile >= nt) return;
  int tmv = tmap[tile];
  int e = tmv & 7, base = tmv >> 3;
  int n_e = cnt[e];
  int offe = off[e];
  int n0 = blockIdx.y * 128;

  __shared__ unsigned short As[64 * 72];
  __shared__ unsigned short Bs[128 * 72];
  __shared__ int tok_s[64];
  __shared__ float wgt_s[64];

  int tid = threadIdx.x;
  if (tid < 64){
    int gr = base + tid;
    int gi = (gr < n_e) ? gr : (n_e - 1);
    tok_s[tid] = tok[e * T_TOK + gi];
    wgt_s[tid] = wgt[e * T_TOK + gi];
  }

  int lane = tid & 63, wid = tid >> 6;
  int cc = (tid & 7) * 8;
  int sr = tid >> 3;

  const unsigned short* a_src[2];
  #pragma unroll
  for (int j = 0; j < 2; j++){
    int gr = base + sr + j * 32; if (gr >= n_e) gr = n_e - 1;
    a_src[j] = h_buf + (size_t)(offe + gr) * I_DIM + cc;
  }
  const unsigned short* b_src[4];
  const unsigned short* Bg = w2t + ((size_t)e * H_DIM + n0) * I_DIM;
  #pragma unroll
  for (int j = 0; j < 4; j++)
    b_src[j] = Bg + (size_t)(sr + j * 32) * I_DIM + cc;

  int wm = (wid >> 1) * 32, wn = (wid & 1) * 64;
  int rfrag = lane & 15;
  int koff  = (lane >> 4) * 8;

  f32x4 acc[2][4] = {};

  for (int k0 = 0; k0 < I_DIM; k0 += 64){
    #pragma unroll
    for (int j = 0; j < 2; j++)
      *reinterpret_cast<int4*>(&As[(sr + j * 32) * 72 + cc]) =
          *reinterpret_cast<const int4*>(a_src[j] + k0);
    #pragma unroll
    for (int j = 0; j < 4; j++)
      *reinterpret_cast<int4*>(&Bs[(sr + j * 32) * 72 + cc]) =
          *reinterpret_cast<const int4*>(b_src[j] + k0);
    __syncthreads();
    #pragma unroll
    for (int kk = 0; kk < 2; kk++){
      s16x8 af[2], bfr[4];
      #pragma unroll
      for (int fm = 0; fm < 2; fm++)
        af[fm] = *reinterpret_cast<const s16x8*>(&As[(wm + fm * 16 + rfrag) * 72 + kk * 32 + koff]);
      #pragma unroll
      for (int fn = 0; fn < 4; fn++)
        bfr[fn] = *reinterpret_cast<const s16x8*>(&Bs[(wn + fn * 16 + rfrag) * 72 + kk * 32 + koff]);
      #pragma unroll
      for (int fm = 0; fm < 2; fm++){
        #pragma unroll
        for (int fn = 0; fn < 4; fn++)
          acc[fm][fn] = __builtin_amdgcn_mfma_f32_16x16x32_bf16(af[fm], bfr[fn], acc[fm][fn], 0, 0, 0);
      }
    }
    __syncthreads();
  }

  int rbase = wm + (lane >> 4) * 4;
  #pragma unroll
  for (int fm = 0; fm < 2; fm++){
    #pragma unroll
    for (int j = 0; j < 4; j++){
      int row_l = rbase + fm * 16 + j;
      int gr = base + row_l;
      if (gr < n_e){
        int t = tok_s[row_l];
        float wv = wgt_s[row_l];
        #pragma unroll
        for (int fn = 0; fn < 4; fn++){
          int col = n0 + wn + fn * 16 + rfrag;
          float y = acc[fm][fn][j] + b2[e * H_DIM + col];
          atomicAdd(out + (size_t)t * H_DIM + col, wv * y);
        }
      }
    }
  }
}

extern "C" void kernel_launch(void* const* d_in, const int* in_sizes, int n_in,
                              void* d_out, int out_size, void* d_ws, size_t ws_size,
                              hipStream_t stream){
  const float* x  = (const float*)d_in[0];
  const float* gw = (const float*)d_in[1];
  const float* w1 = (const float*)d_in[2];
  const float* b1 = (const float*)d_in[3];
  const float* w2 = (const float*)d_in[4];
  const float* b2 = (const float*)d_in[5];
  float* out = (float*)d_out;

  char* ws = (char*)d_ws;
  int*   cnt  = (int*)(ws);                                   // 32 B
  int*   off  = (int*)(ws + 64);                              // 9 ints
  int*   tmap = (int*)(ws + 128);                             // up to 512 ints
  int*   tok  = (int*)(ws + 4096);                            // 256 KB
  float* wgt  = (float*)(ws + 4096 + 262144);                 // 256 KB
  unsigned short* xb    = (unsigned short*)(ws + 528384);     // 8 MB
  unsigned short* w1t   = (unsigned short*)(ws + 8916992);    // 8 MB  [E][I][H]
  unsigned short* w2t   = (unsigned short*)(ws + 17305600);   // 8 MB  [E][H][I]
  unsigned short* h_buf = (unsigned short*)(ws + 25694208);   // 32 MB
  int*   eab = (int*)(ws + 59248640);                         // 32 KB
  float* wab = (float*)(ws + 59281408);                       // 64 KB

  hipMemsetAsync(d_out, 0, (size_t)out_size * 4, stream);
  hipMemsetAsync(cnt, 0, 64, stream);

  transpose_cvt<<<dim3(16, 8, 8), 256, 0, stream>>>(w1, w1t, 512, 1024);
  transpose_cvt<<<dim3(8, 16, 8), 256, 0, stream>>>(w2, w2t, 1024, 512);

  float* logits_out = out + (size_t)T_TOK * H_DIM;
  router_kernel<<<2048, 256, 0, stream>>>(x, gw, logits_out, eab, wab, xb);
  scatter_kernel<<<32, 256, 0, stream>>>(eab, wab, cnt, tok, wgt);
  build_tiles<<<1, 64, 0, stream>>>(cnt, off, tmap);

  gemm1_kernel<<<dim3(264, 8), 256, 0, stream>>>(xb, w1t, b1, cnt, off, tok, tmap, h_buf);
  gemm2_kernel<<<dim3(264, 4), 256, 0, stream>>>(h_buf, w2t, b2, cnt, off, tok, wgt, tmap, out);
}

// Round 10
// 214.516 us; speedup vs baseline: 2.5898x; 1.1054x over previous
//
#include <hip/hip_runtime.h>
#include <hip/hip_bf16.h>

typedef __attribute__((ext_vector_type(8))) short s16x8;
typedef __attribute__((ext_vector_type(4))) float f32x4;

#define T_TOK 8192
#define H_DIM 512
#define I_DIM 1024

static __device__ __forceinline__ unsigned short f2bf(float f){
  unsigned int b = __builtin_bit_cast(unsigned int, f);
  b += 0x7FFFu + ((b >> 16) & 1u);           // round-to-nearest-even
  return (unsigned short)(b >> 16);
}

// global -> LDS direct copy, 16B per lane. LDS dest must be WAVE-UNIFORM base;
// HW writes lane l at base + l*16. Global src is per-lane.
static __device__ __forceinline__ void g2l16(const void* g, void* l){
  __builtin_amdgcn_global_load_lds(
      (__attribute__((address_space(1))) void*)(unsigned long long)g,
      (__attribute__((address_space(3))) void*)(unsigned int)(unsigned long long)l,
      16, 0, 0);
}

// ---- per-expert transpose + convert: in [E][R][C] f32 -> out [E][C][R] bf16 ----
__global__ void transpose_cvt(const float* __restrict__ in, unsigned short* __restrict__ out,
                              int R, int C){
  __shared__ unsigned short tile[64][72];
  int e = blockIdx.z;
  const float* src = in + (size_t)e * R * C;
  unsigned short* dst = out + (size_t)e * R * C;
  int r0 = blockIdx.y * 64, c0 = blockIdx.x * 64;
  int tr = threadIdx.x >> 4;           // 0..15
  int tc = (threadIdx.x & 15) * 4;     // 0..60
  #pragma unroll
  for (int i = 0; i < 4; i++){
    int r = tr + i * 16;
    float4 v = *reinterpret_cast<const float4*>(src + (size_t)(r0 + r) * C + c0 + tc);
    tile[tc + 0][r] = f2bf(v.x);
    tile[tc + 1][r] = f2bf(v.y);
    tile[tc + 2][r] = f2bf(v.z);
    tile[tc + 3][r] = f2bf(v.w);
  }
  __syncthreads();
  #pragma unroll
  for (int i = 0; i < 4; i++){
    int cl = tr + i * 16;              // col of original = row of transposed
    ushort4 o;
    o.x = tile[cl][tc + 0]; o.y = tile[cl][tc + 1];
    o.z = tile[cl][tc + 2]; o.w = tile[cl][tc + 3];
    *reinterpret_cast<ushort4*>(dst + (size_t)(c0 + cl) * R + r0 + tc) = o;
  }
}

// ---- router: logits (fp32) + top-2 + fused x->bf16 conversion ----
__global__ void router_kernel(const float* __restrict__ x, const float* __restrict__ gw,
                              float* __restrict__ logits_out,
                              int* __restrict__ eab, float* __restrict__ wab,
                              unsigned short* __restrict__ xb){
  int wave = threadIdx.x >> 6;
  int lane = threadIdx.x & 63;
  int t = blockIdx.x * 4 + wave;
  const float* xr = x + (size_t)t * H_DIM;
  float xv[8];
  *reinterpret_cast<float4*>(&xv[0]) = *reinterpret_cast<const float4*>(xr + lane * 8);
  *reinterpret_cast<float4*>(&xv[4]) = *reinterpret_cast<const float4*>(xr + lane * 8 + 4);
  s16x8 xo;
  #pragma unroll
  for (int m = 0; m < 8; m++) xo[m] = (short)f2bf(xv[m]);
  *reinterpret_cast<s16x8*>(xb + (size_t)t * H_DIM + lane * 8) = xo;

  float l[8];
  #pragma unroll
  for (int e = 0; e < 8; e++){
    const float* g = gw + e * H_DIM + lane * 8;
    float4 g0 = *reinterpret_cast<const float4*>(g);
    float4 g1 = *reinterpret_cast<const float4*>(g + 4);
    float s = xv[0]*g0.x + xv[1]*g0.y + xv[2]*g0.z + xv[3]*g0.w
            + xv[4]*g1.x + xv[5]*g1.y + xv[6]*g1.z + xv[7]*g1.w;
    #pragma unroll
    for (int o = 32; o >= 1; o >>= 1) s += __shfl_xor(s, o);
    l[e] = s;
  }
  if (lane == 0){
    float4 L0 = make_float4(l[0], l[1], l[2], l[3]);
    float4 L1 = make_float4(l[4], l[5], l[6], l[7]);
    *reinterpret_cast<float4*>(logits_out + (size_t)t * 8)     = L0;
    *reinterpret_cast<float4*>(logits_out + (size_t)t * 8 + 4) = L1;
    float m = l[0];
    #pragma unroll
    for (int e = 1; e < 8; e++) m = fmaxf(m, l[e]);
    float p[8]; float Z = 0.f;
    #pragma unroll
    for (int e = 0; e < 8; e++){ p[e] = expf(l[e] - m); Z += p[e]; }
    int a = 0;
    #pragma unroll
    for (int e = 1; e < 8; e++) if (p[e] > p[a]) a = e;   // earliest max: matches top_k
    int b = (a == 0) ? 1 : 0;
    #pragma unroll
    for (int e = 0; e < 8; e++) if (e != a && p[e] > p[b]) b = e;
    float pa = p[a] / Z, pb = p[b] / Z;
    float inv = 0.5f / (pa + pb + 1e-20f);                // norm_topk + /TOP_K
    eab[t] = a | (b << 8);
    *reinterpret_cast<float2*>(wab + (size_t)t * 2) = make_float2(pa * inv, pb * inv);
  }
}

// ---- router stage 2: ballot-aggregated scatter into per-expert lists ----
__global__ __launch_bounds__(256) void scatter_kernel(
    const int* __restrict__ eab, const float* __restrict__ wab,
    int* __restrict__ cnt, int* __restrict__ tok, float* __restrict__ wgt){
  __shared__ int wcnt[8][8];
  __shared__ int lbase[8][8];
  __shared__ int gbase[8];
  int tid = threadIdx.x;
  int wave = tid >> 6, lane = tid & 63;
  int t = blockIdx.x * 256 + tid;
  int ee = eab[t];
  int ea = ee & 0xff, eb = ee >> 8;
  float2 wv = *reinterpret_cast<const float2*>(wab + (size_t)t * 2);
  unsigned long long mlt = (1ull << lane) - 1ull;
  int rankA = 0, rankB = 0;
  #pragma unroll
  for (int e = 0; e < 8; e++){
    unsigned long long mA = __ballot(ea == e);
    unsigned long long mB = __ballot(eb == e);
    if (ea == e) rankA = __popcll(mA & mlt);
    if (eb == e) rankB = __popcll(mB & mlt);
    if (lane == 0){
      wcnt[wave * 2 + 0][e] = __popcll(mA);
      wcnt[wave * 2 + 1][e] = __popcll(mB);
    }
  }
  __syncthreads();
  if (tid < 8){
    int s = 0;
    #pragma unroll
    for (int w = 0; w < 8; w++){ lbase[w][tid] = s; s += wcnt[w][tid]; }
    gbase[tid] = atomicAdd(&cnt[tid], s);
  }
  __syncthreads();
  int ia = gbase[ea] + lbase[wave * 2 + 0][ea] + rankA;
  tok[ea * T_TOK + ia] = t; wgt[ea * T_TOK + ia] = wv.x;
  int ib = gbase[eb] + lbase[wave * 2 + 1][eb] + rankB;
  tok[eb * T_TOK + ib] = t; wgt[eb * T_TOK + ib] = wv.y;
}

// ---- build per-expert offsets + exact 64-row tile map ----
__global__ void build_tiles(const int* __restrict__ cnt, int* __restrict__ off,
                            int* __restrict__ tmap){
  if (threadIdx.x == 0){
    int s = 0;
    for (int e = 0; e < 8; e++){ off[e] = s; s += cnt[e]; }
    int nt = 0;
    for (int e = 0; e < 8; e++)
      for (int b = 0; b < cnt[e]; b += 64)
        tmap[nt++] = (b << 3) | e;      // pack: base<<3 | expert
    off[8] = nt;                        // total tiles (<= 264)
  }
}

// ---- GEMM1: h = relu(gather(xb) @ w1t^T + b1). 64x128 tile, dbuf gload_lds pipeline ----
__global__ __launch_bounds__(256) void gemm1_kernel(
    const unsigned short* __restrict__ xb, const unsigned short* __restrict__ w1t,
    const float* __restrict__ b1,
    const int* __restrict__ cnt, const int* __restrict__ off,
    const int* __restrict__ tok, const int* __restrict__ tmap,
    unsigned short* __restrict__ h_buf){
  int nt = off[8];
  int tile = blockIdx.x;
  if (tile >= nt) return;
  int tmv = tmap[tile];
  int e = tmv & 7, base = tmv >> 3;
  int n_e = cnt[e];
  int offe = off[e];
  int n0 = blockIdx.y * 128;

  __shared__ unsigned short As[2][64 * 64];   // linear, gload_lds dest
  __shared__ unsigned short Bs[2][128 * 64];

  int tid = threadIdx.x;
  int lane = tid & 63, w = tid >> 6;
  // source-side XOR swizzle: lane fetches granule gc so LDS[row][g] = global[row][g^(row&7)]
  int gc = (lane & 7) ^ (lane >> 3);          // granule (16B units) this lane fetches

  // A: wave w covers rows [w*16, w*16+16), 2 calls x 8 rows
  const unsigned short* a_src[2];
  #pragma unroll
  for (int j = 0; j < 2; j++){
    int r = w * 16 + j * 8 + (lane >> 3);
    int gr = base + r; if (gr >= n_e) gr = n_e - 1;
    a_src[j] = xb + (size_t)tok[e * T_TOK + gr] * H_DIM + gc * 8;
  }
  // B: wave w covers rows [w*32, w*32+32), 4 calls x 8 rows
  const unsigned short* b_src[4];
  const unsigned short* Bg = w1t + ((size_t)e * I_DIM + n0) * H_DIM;
  #pragma unroll
  for (int j = 0; j < 4; j++)
    b_src[j] = Bg + (size_t)(w * 32 + j * 8 + (lane >> 3)) * H_DIM + gc * 8;

  int wm = (w >> 1) * 32, wn = (w & 1) * 64;
  int rfrag = lane & 15;
  int g4 = lane >> 4;                          // granule sub-index within kk (0..3)

  f32x4 acc[2][4] = {};

  // prologue: stage k=0 into buf 0
  #pragma unroll
  for (int j = 0; j < 2; j++) g2l16(a_src[j], &As[0][(w * 16 + j * 8) * 64]);
  #pragma unroll
  for (int j = 0; j < 4; j++) g2l16(b_src[j], &Bs[0][(w * 32 + j * 8) * 64]);
  __syncthreads();

  int cur = 0;
  const int NSTEP = H_DIM / 64;                // 8
  for (int t = 0; t < NSTEP; t++){
    if (t + 1 < NSTEP){
      int k1 = (t + 1) * 64;
      #pragma unroll
      for (int j = 0; j < 2; j++) g2l16(a_src[j] + k1, &As[cur ^ 1][(w * 16 + j * 8) * 64]);
      #pragma unroll
      for (int j = 0; j < 4; j++) g2l16(b_src[j] + k1, &Bs[cur ^ 1][(w * 32 + j * 8) * 64]);
    }
    const unsigned short* Ac = &As[cur][0];
    const unsigned short* Bc = &Bs[cur][0];
    #pragma unroll
    for (int kk = 0; kk < 2; kk++){
      int g = kk * 4 + g4;
      s16x8 af[2], bfr[4];
      #pragma unroll
      for (int fm = 0; fm < 2; fm++){
        int r = wm + fm * 16 + rfrag;
        af[fm] = *reinterpret_cast<const s16x8*>(&Ac[r * 64 + ((g ^ (r & 7)) * 8)]);
      }
      #pragma unroll
      for (int fn = 0; fn < 4; fn++){
        int r = wn + fn * 16 + rfrag;
        bfr[fn] = *reinterpret_cast<const s16x8*>(&Bc[r * 64 + ((g ^ (r & 7)) * 8)]);
      }
      #pragma unroll
      for (int fm = 0; fm < 2; fm++){
        #pragma unroll
        for (int fn = 0; fn < 4; fn++)
          acc[fm][fn] = __builtin_amdgcn_mfma_f32_16x16x32_bf16(af[fm], bfr[fn], acc[fm][fn], 0, 0, 0);
      }
    }
    __syncthreads();                           // drains vmcnt for buf[cur^1] + syncs
    cur ^= 1;
  }

  int rbase = wm + (lane >> 4) * 4;
  #pragma unroll
  for (int fm = 0; fm < 2; fm++){
    #pragma unroll
    for (int j = 0; j < 4; j++){
      int gr = base + rbase + fm * 16 + j;
      if (gr < n_e){
        #pragma unroll
        for (int fn = 0; fn < 4; fn++){
          int col = n0 + wn + fn * 16 + rfrag;
          float h = acc[fm][fn][j] + b1[e * I_DIM + col];
          h_buf[(size_t)(offe + gr) * I_DIM + col] = f2bf(fmaxf(h, 0.f));
        }
      }
    }
  }
}

// ---- GEMM2: y = h @ w2t^T + b2; out[t] += w * y. 64x128 tile, dbuf gload_lds pipeline ----
__global__ __launch_bounds__(256) void gemm2_kernel(
    const unsigned short* __restrict__ h_buf, const unsigned short* __restrict__ w2t,
    const float* __restrict__ b2,
    const int* __restrict__ cnt, const int* __restrict__ off,
    const int* __restrict__ tok, const float* __restrict__ wgt,
    const int* __restrict__ tmap,
    float* __restrict__ out){
  int nt = off[8];
  int tile = blockIdx.x;
  if (tile >= nt) return;
  int tmv = tmap[tile];
  int e = tmv & 7, base = tmv >> 3;
  int n_e = cnt[e];
  int offe = off[e];
  int n0 = blockIdx.y * 128;

  __shared__ unsigned short As[2][64 * 64];
  __shared__ unsigned short Bs[2][128 * 64];
  __shared__ int tok_s[64];
  __shared__ float wgt_s[64];

  int tid = threadIdx.x;
  if (tid < 64){
    int gr = base + tid;
    int gi = (gr < n_e) ? gr : (n_e - 1);
    tok_s[tid] = tok[e * T_TOK + gi];
    wgt_s[tid] = wgt[e * T_TOK + gi];
  }

  int lane = tid & 63, w = tid >> 6;
  int gc = (lane & 7) ^ (lane >> 3);

  const unsigned short* a_src[2];
  #pragma unroll
  for (int j = 0; j < 2; j++){
    int r = w * 16 + j * 8 + (lane >> 3);
    int gr = base + r; if (gr >= n_e) gr = n_e - 1;
    a_src[j] = h_buf + (size_t)(offe + gr) * I_DIM + gc * 8;
  }
  const unsigned short* b_src[4];
  const unsigned short* Bg = w2t + ((size_t)e * H_DIM + n0) * I_DIM;
  #pragma unroll
  for (int j = 0; j < 4; j++)
    b_src[j] = Bg + (size_t)(w * 32 + j * 8 + (lane >> 3)) * I_DIM + gc * 8;

  int wm = (w >> 1) * 32, wn = (w & 1) * 64;
  int rfrag = lane & 15;
  int g4 = lane >> 4;

  f32x4 acc[2][4] = {};

  #pragma unroll
  for (int j = 0; j < 2; j++) g2l16(a_src[j], &As[0][(w * 16 + j * 8) * 64]);
  #pragma unroll
  for (int j = 0; j < 4; j++) g2l16(b_src[j], &Bs[0][(w * 32 + j * 8) * 64]);
  __syncthreads();

  int cur = 0;
  const int NSTEP = I_DIM / 64;                // 16
  for (int t = 0; t < NSTEP; t++){
    if (t + 1 < NSTEP){
      int k1 = (t + 1) * 64;
      #pragma unroll
      for (int j = 0; j < 2; j++) g2l16(a_src[j] + k1, &As[cur ^ 1][(w * 16 + j * 8) * 64]);
      #pragma unroll
      for (int j = 0; j < 4; j++) g2l16(b_src[j] + k1, &Bs[cur ^ 1][(w * 32 + j * 8) * 64]);
    }
    const unsigned short* Ac = &As[cur][0];
    const unsigned short* Bc = &Bs[cur][0];
    #pragma unroll
    for (int kk = 0; kk < 2; kk++){
      int g = kk * 4 + g4;
      s16x8 af[2], bfr[4];
      #pragma unroll
      for (int fm = 0; fm < 2; fm++){
        int r = wm + fm * 16 + rfrag;
        af[fm] = *reinterpret_cast<const s16x8*>(&Ac[r * 64 + ((g ^ (r & 7)) * 8)]);
      }
      #pragma unroll
      for (int fn = 0; fn < 4; fn++){
        int r = wn + fn * 16 + rfrag;
        bfr[fn] = *reinterpret_cast<const s16x8*>(&Bc[r * 64 + ((g ^ (r & 7)) * 8)]);
      }
      #pragma unroll
      for (int fm = 0; fm < 2; fm++){
        #pragma unroll
        for (int fn = 0; fn < 4; fn++)
          acc[fm][fn] = __builtin_amdgcn_mfma_f32_16x16x32_bf16(af[fm], bfr[fn], acc[fm][fn], 0, 0, 0);
      }
    }
    __syncthreads();
    cur ^= 1;
  }

  int rbase = wm + (lane >> 4) * 4;
  #pragma unroll
  for (int fm = 0; fm < 2; fm++){
    #pragma unroll
    for (int j = 0; j < 4; j++){
      int row_l = rbase + fm * 16 + j;
      int gr = base + row_l;
      if (gr < n_e){
        int t = tok_s[row_l];
        float wv = wgt_s[row_l];
        #pragma unroll
        for (int fn = 0; fn < 4; fn++){
          int col = n0 + wn + fn * 16 + rfrag;
          float y = acc[fm][fn][j] + b2[e * H_DIM + col];
          atomicAdd(out + (size_t)t * H_DIM + col, wv * y);
        }
      }
    }
  }
}

extern "C" void kernel_launch(void* const* d_in, const int* in_sizes, int n_in,
                              void* d_out, int out_size, void* d_ws, size_t ws_size,
                              hipStream_t stream){
  const float* x  = (const float*)d_in[0];
  const float* gw = (const float*)d_in[1];
  const float* w1 = (const float*)d_in[2];
  const float* b1 = (const float*)d_in[3];
  const float* w2 = (const float*)d_in[4];
  const float* b2 = (const float*)d_in[5];
  float* out = (float*)d_out;

  char* ws = (char*)d_ws;
  int*   cnt  = (int*)(ws);                                   // 32 B
  int*   off  = (int*)(ws + 64);                              // 9 ints
  int*   tmap = (int*)(ws + 128);                             // up to 512 ints
  int*   tok  = (int*)(ws + 4096);                            // 256 KB
  float* wgt  = (float*)(ws + 4096 + 262144);                 // 256 KB
  unsigned short* xb    = (unsigned short*)(ws + 528384);     // 8 MB
  unsigned short* w1t   = (unsigned short*)(ws + 8916992);    // 8 MB  [E][I][H]
  unsigned short* w2t   = (unsigned short*)(ws + 17305600);   // 8 MB  [E][H][I]
  unsigned short* h_buf = (unsigned short*)(ws + 25694208);   // 32 MB
  int*   eab = (int*)(ws + 59248640);                         // 32 KB
  float* wab = (float*)(ws + 59281408);                       // 64 KB

  hipMemsetAsync(d_out, 0, (size_t)out_size * 4, stream);
  hipMemsetAsync(cnt, 0, 64, stream);

  transpose_cvt<<<dim3(16, 8, 8), 256, 0, stream>>>(w1, w1t, 512, 1024);
  transpose_cvt<<<dim3(8, 16, 8), 256, 0, stream>>>(w2, w2t, 1024, 512);

  float* logits_out = out + (size_t)T_TOK * H_DIM;
  router_kernel<<<2048, 256, 0, stream>>>(x, gw, logits_out, eab, wab, xb);
  scatter_kernel<<<32, 256, 0, stream>>>(eab, wab, cnt, tok, wgt);
  build_tiles<<<1, 64, 0, stream>>>(cnt, off, tmap);

  gemm1_kernel<<<dim3(264, 8), 256, 0, stream>>>(xb, w1t, b1, cnt, off, tok, tmap, h_buf);
  gemm2_kernel<<<dim3(264, 4), 256, 0, stream>>>(h_buf, w2t, b2, cnt, off, tok, wgt, tmap, out);
}